// Round 1
// baseline (2741.008 us; speedup 1.0000x reference)
//
#include <hip/hip_runtime.h>

#define D 128

// y[row[e]] += val[e] * x[col[e]]  -- 32 threads per edge, float4 per thread
__global__ __launch_bounds__(256) void spmm_atomic_kernel(
    const int* __restrict__ row, const int* __restrict__ col,
    const float* __restrict__ val, const float* __restrict__ x,
    float* __restrict__ y, int E) {
  long idx = (long)blockIdx.x * blockDim.x + threadIdx.x;
  int e = (int)(idx >> 5);
  if (e >= E) return;
  int q = (int)(idx & 31);
  int r = row[e];
  int c = col[e];
  float v = val[e];
  const float4 xv = *reinterpret_cast<const float4*>(x + (long)c * D + q * 4);
  float* yp = y + (long)r * D + q * 4;
  atomicAdd(yp + 0, v * xv.x);
  atomicAdd(yp + 1, v * xv.y);
  atomicAdd(yp + 2, v * xv.z);
  atomicAdd(yp + 3, v * xv.w);
}

// out = (0.5*h2 - 0.5*feat) @ W    [N,128] x [128,128] fp32, vector ALU
__global__ __launch_bounds__(256) void combine_gemm_kernel(
    const float* __restrict__ h2, const float* __restrict__ feat,
    const float* __restrict__ W, float* __restrict__ out, int N) {
  __shared__ float Ws[D][D];   // 64 KB
  __shared__ float Xs[32][D];  // 16 KB
  const int t = threadIdx.x;

  // stage W: 16384 floats, 256 threads x 16 float4
#pragma unroll
  for (int i = 0; i < 16; ++i) {
    int o = i * 1024 + t * 4;
    *reinterpret_cast<float4*>(&Ws[0][0] + o) =
        *reinterpret_cast<const float4*>(W + o);
  }

  const int rb = blockIdx.x * 32;
  // stage X tile = 0.5*h2 - 0.5*feat : 4096 floats
#pragma unroll
  for (int i = 0; i < 4; ++i) {
    int o = i * 1024 + t * 4;
    int r = o >> 7;
    int cc = o & 127;
    float4 xv = {0.f, 0.f, 0.f, 0.f};
    if (rb + r < N) {
      float4 hv = *reinterpret_cast<const float4*>(h2 + (long)(rb + r) * D + cc);
      float4 fv = *reinterpret_cast<const float4*>(feat + (long)(rb + r) * D + cc);
      xv.x = 0.5f * (hv.x - fv.x);
      xv.y = 0.5f * (hv.y - fv.y);
      xv.z = 0.5f * (hv.z - fv.z);
      xv.w = 0.5f * (hv.w - fv.w);
    }
    *reinterpret_cast<float4*>(&Xs[r][cc]) = xv;
  }
  __syncthreads();

  const int j0 = (t & 31) * 4;   // output col group
  const int i0 = (t >> 5) * 4;   // output row group (within tile)
  float4 acc[4];
#pragma unroll
  for (int ii = 0; ii < 4; ++ii) acc[ii] = {0.f, 0.f, 0.f, 0.f};

#pragma unroll 8
  for (int kb = 0; kb < 32; ++kb) {
    float4 xr[4], wr[4];
#pragma unroll
    for (int ii = 0; ii < 4; ++ii)
      xr[ii] = *reinterpret_cast<const float4*>(&Xs[i0 + ii][kb * 4]);
#pragma unroll
    for (int kk = 0; kk < 4; ++kk)
      wr[kk] = *reinterpret_cast<const float4*>(&Ws[kb * 4 + kk][j0]);
#pragma unroll
    for (int ii = 0; ii < 4; ++ii) {
      const float* xp = &xr[ii].x;
#pragma unroll
      for (int kk = 0; kk < 4; ++kk) {
        float xk = xp[kk];
        acc[ii].x += xk * wr[kk].x;
        acc[ii].y += xk * wr[kk].y;
        acc[ii].z += xk * wr[kk].z;
        acc[ii].w += xk * wr[kk].w;
      }
    }
  }

#pragma unroll
  for (int ii = 0; ii < 4; ++ii) {
    int r = rb + i0 + ii;
    if (r < N)
      *reinterpret_cast<float4*>(out + (long)r * D + j0) = acc[ii];
  }
}

extern "C" void kernel_launch(void* const* d_in, const int* in_sizes, int n_in,
                              void* d_out, int out_size, void* d_ws, size_t ws_size,
                              hipStream_t stream) {
  const float* feature = (const float*)d_in[0];
  const int* adj_row   = (const int*)d_in[1];
  const int* adj_col   = (const int*)d_in[2];
  const float* adj_val = (const float*)d_in[3];
  const float* weight  = (const float*)d_in[4];
  float* out = (float*)d_out;

  const int N = in_sizes[0] / D;
  const int E = in_sizes[1];

  float* h1 = out;            // h1 lives in d_out (dead after spmm2)
  float* h2 = (float*)d_ws;   // h2 in workspace (N*D*4 = 25.6 MB)

  const size_t hbytes = (size_t)N * D * sizeof(float);
  const long items = (long)E * 32;
  const int spmm_blocks = (int)((items + 255) / 256);

  // h1 = A @ feature
  hipMemsetAsync(h1, 0, hbytes, stream);
  spmm_atomic_kernel<<<spmm_blocks, 256, 0, stream>>>(adj_row, adj_col, adj_val,
                                                      feature, h1, E);
  // h2 = A @ h1
  hipMemsetAsync(h2, 0, hbytes, stream);
  spmm_atomic_kernel<<<spmm_blocks, 256, 0, stream>>>(adj_row, adj_col, adj_val,
                                                      h1, h2, E);
  // out = (0.5*h2 - 0.5*feature) @ W
  combine_gemm_kernel<<<(N + 31) / 32, 256, 0, stream>>>(h2, feature, weight,
                                                         out, N);
}

// Round 2
// 324.122 us; speedup vs baseline: 8.4567x; 8.4567x over previous
//
#include <hip/hip_runtime.h>

#define D 128

// ---------------- CSR build ----------------

__global__ __launch_bounds__(256) void hist_kernel(const int* __restrict__ row,
                                                   int* __restrict__ cnt, int E) {
  int i = blockIdx.x * blockDim.x + threadIdx.x;
  if (i < E) atomicAdd(&cnt[row[i]], 1);
}

// single-block exclusive scan of cnt[N] -> row_ptr[N] (+row_ptr[N]=E) and cursor[N]
// cursor may alias cnt (each index read-then-written by the same thread).
__global__ __launch_bounds__(1024) void scan_kernel(const int* __restrict__ cnt,
                                                    int* __restrict__ row_ptr,
                                                    int* __restrict__ cursor,
                                                    int N, int E) {
  __shared__ int wsum[16];
  __shared__ int s_carry;
  const int t = threadIdx.x;
  const int lane = t & 63;
  const int wave = t >> 6;
  if (t == 0) s_carry = 0;
  __syncthreads();
  for (int base = 0; base < N; base += 8192) {
    int v[8];
    int s = 0;
#pragma unroll
    for (int i = 0; i < 8; ++i) {
      int idx = base + t * 8 + i;
      v[i] = (idx < N) ? cnt[idx] : 0;
      s += v[i];
    }
    // inclusive wave scan of s
    int x = s;
#pragma unroll
    for (int off = 1; off < 64; off <<= 1) {
      int y = __shfl_up(x, off, 64);
      if (lane >= off) x += y;
    }
    if (lane == 63) wsum[wave] = x;
    __syncthreads();
    if (wave == 0) {
      int ws = (lane < 16) ? wsum[lane] : 0;
      int xx = ws;
#pragma unroll
      for (int off = 1; off < 16; off <<= 1) {
        int y = __shfl_up(xx, off, 64);
        if (lane >= off) xx += y;
      }
      if (lane < 16) wsum[lane] = xx - ws;  // exclusive wave prefix
    }
    __syncthreads();
    int carry = s_carry;
    int run = carry + wsum[wave] + (x - s);  // exclusive prefix for this thread
#pragma unroll
    for (int i = 0; i < 8; ++i) {
      int idx = base + t * 8 + i;
      if (idx < N) { row_ptr[idx] = run; cursor[idx] = run; }
      run += v[i];
    }
    __syncthreads();
    if (t == 1023) s_carry = carry + wsum[15] + x;
    __syncthreads();
  }
  if (t == 0) row_ptr[N] = E;
}

__global__ __launch_bounds__(256) void scatter_kernel(
    const int* __restrict__ row, const int* __restrict__ col,
    const float* __restrict__ val, int* __restrict__ cursor,
    int* __restrict__ csr_col, float* __restrict__ csr_val, int E) {
  int i = blockIdx.x * blockDim.x + threadIdx.x;
  if (i < E) {
    int r = row[i];
    int p = atomicAdd(&cursor[r], 1);
    csr_col[p] = col[i];
    csr_val[p] = val[i];
  }
}

// ---------------- CSR SpMM: y[r] = sum val*x[col], one 32-lane group per row ----

__global__ __launch_bounds__(256) void spmm_csr_kernel(
    const int* __restrict__ row_ptr, const int* __restrict__ csr_col,
    const float* __restrict__ csr_val, const float* __restrict__ x,
    float* __restrict__ y, int N) {
  int r = blockIdx.x * (blockDim.x >> 5) + (threadIdx.x >> 5);
  int q = threadIdx.x & 31;
  if (r >= N) return;
  int s = row_ptr[r], e = row_ptr[r + 1];
  float4 acc = {0.f, 0.f, 0.f, 0.f};
  for (int k = s; k < e; ++k) {
    int c = csr_col[k];
    float v = csr_val[k];
    float4 xv = *reinterpret_cast<const float4*>(x + (long)c * D + q * 4);
    acc.x += v * xv.x; acc.y += v * xv.y; acc.z += v * xv.z; acc.w += v * xv.w;
  }
  *reinterpret_cast<float4*>(y + (long)r * D + q * 4) = acc;
}

// ---------------- fused: out = (0.5*(A@h1) - 0.5*feat) @ W ----------------
// 8 groups x 4 rows per block; z rows staged in LDS; W streamed via L1/L2.

__global__ __launch_bounds__(256) void fused_spmm2_gemm_kernel(
    const int* __restrict__ row_ptr, const int* __restrict__ csr_col,
    const float* __restrict__ csr_val, const float* __restrict__ h1,
    const float* __restrict__ feat, const float* __restrict__ W,
    float* __restrict__ out, int N) {
  __shared__ float zbuf[8][4][128];
  const int g = threadIdx.x >> 5;
  const int q = threadIdx.x & 31;
  const int row0 = blockIdx.x * 32 + g * 4;

#pragma unroll
  for (int rr = 0; rr < 4; ++rr) {
    int r = row0 + rr;
    float4 acc = {0.f, 0.f, 0.f, 0.f};
    if (r < N) {
      int s = row_ptr[r], e = row_ptr[r + 1];
      for (int k = s; k < e; ++k) {
        int c = csr_col[k];
        float v = csr_val[k];
        float4 xv = *reinterpret_cast<const float4*>(h1 + (long)c * D + q * 4);
        acc.x += v * xv.x; acc.y += v * xv.y; acc.z += v * xv.z; acc.w += v * xv.w;
      }
      float4 fv = *reinterpret_cast<const float4*>(feat + (long)r * D + q * 4);
      acc.x = 0.5f * (acc.x - fv.x);
      acc.y = 0.5f * (acc.y - fv.y);
      acc.z = 0.5f * (acc.z - fv.z);
      acc.w = 0.5f * (acc.w - fv.w);
    }
    *reinterpret_cast<float4*>(&zbuf[g][rr][q * 4]) = acc;
  }
  __syncthreads();

  const int j0 = q * 4;
  float4 o[4];
#pragma unroll
  for (int rr = 0; rr < 4; ++rr) o[rr] = {0.f, 0.f, 0.f, 0.f};
#pragma unroll 4
  for (int k = 0; k < D; ++k) {
    float4 wv = *reinterpret_cast<const float4*>(W + k * D + j0);
#pragma unroll
    for (int rr = 0; rr < 4; ++rr) {
      float zv = zbuf[g][rr][k];
      o[rr].x += zv * wv.x;
      o[rr].y += zv * wv.y;
      o[rr].z += zv * wv.z;
      o[rr].w += zv * wv.w;
    }
  }
#pragma unroll
  for (int rr = 0; rr < 4; ++rr) {
    int r = row0 + rr;
    if (r < N) *reinterpret_cast<float4*>(out + (long)r * D + j0) = o[rr];
  }
}

// ---------------- fallback (round-1) kernels ----------------

__global__ __launch_bounds__(256) void spmm_atomic_kernel(
    const int* __restrict__ row, const int* __restrict__ col,
    const float* __restrict__ val, const float* __restrict__ x,
    float* __restrict__ y, int E) {
  long idx = (long)blockIdx.x * blockDim.x + threadIdx.x;
  int e = (int)(idx >> 5);
  if (e >= E) return;
  int q = (int)(idx & 31);
  int r = row[e];
  int c = col[e];
  float v = val[e];
  const float4 xv = *reinterpret_cast<const float4*>(x + (long)c * D + q * 4);
  float* yp = y + (long)r * D + q * 4;
  atomicAdd(yp + 0, v * xv.x);
  atomicAdd(yp + 1, v * xv.y);
  atomicAdd(yp + 2, v * xv.z);
  atomicAdd(yp + 3, v * xv.w);
}

__global__ __launch_bounds__(256) void combine_gemm_kernel(
    const float* __restrict__ h2, const float* __restrict__ feat,
    const float* __restrict__ W, float* __restrict__ out, int N) {
  __shared__ float Ws[D][D];
  __shared__ float Xs[32][D];
  const int t = threadIdx.x;
#pragma unroll
  for (int i = 0; i < 16; ++i) {
    int o = i * 1024 + t * 4;
    *reinterpret_cast<float4*>(&Ws[0][0] + o) =
        *reinterpret_cast<const float4*>(W + o);
  }
  const int rb = blockIdx.x * 32;
#pragma unroll
  for (int i = 0; i < 4; ++i) {
    int o = i * 1024 + t * 4;
    int r = o >> 7;
    int cc = o & 127;
    float4 xv = {0.f, 0.f, 0.f, 0.f};
    if (rb + r < N) {
      float4 hv = *reinterpret_cast<const float4*>(h2 + (long)(rb + r) * D + cc);
      float4 fv = *reinterpret_cast<const float4*>(feat + (long)(rb + r) * D + cc);
      xv.x = 0.5f * (hv.x - fv.x);
      xv.y = 0.5f * (hv.y - fv.y);
      xv.z = 0.5f * (hv.z - fv.z);
      xv.w = 0.5f * (hv.w - fv.w);
    }
    *reinterpret_cast<float4*>(&Xs[r][cc]) = xv;
  }
  __syncthreads();
  const int j0 = (t & 31) * 4;
  const int i0 = (t >> 5) * 4;
  float4 acc[4];
#pragma unroll
  for (int ii = 0; ii < 4; ++ii) acc[ii] = {0.f, 0.f, 0.f, 0.f};
#pragma unroll 8
  for (int kb = 0; kb < 32; ++kb) {
    float4 xr[4], wr[4];
#pragma unroll
    for (int ii = 0; ii < 4; ++ii)
      xr[ii] = *reinterpret_cast<const float4*>(&Xs[i0 + ii][kb * 4]);
#pragma unroll
    for (int kk = 0; kk < 4; ++kk)
      wr[kk] = *reinterpret_cast<const float4*>(&Ws[kb * 4 + kk][j0]);
#pragma unroll
    for (int ii = 0; ii < 4; ++ii) {
      const float* xp = &xr[ii].x;
#pragma unroll
      for (int kk = 0; kk < 4; ++kk) {
        float xk = xp[kk];
        acc[ii].x += xk * wr[kk].x;
        acc[ii].y += xk * wr[kk].y;
        acc[ii].z += xk * wr[kk].z;
        acc[ii].w += xk * wr[kk].w;
      }
    }
  }
#pragma unroll
  for (int ii = 0; ii < 4; ++ii) {
    int r = rb + i0 + ii;
    if (r < N)
      *reinterpret_cast<float4*>(out + (long)r * D + j0) = acc[ii];
  }
}

// ---------------- host ----------------

static inline size_t align256(size_t x) { return (x + 255) & ~(size_t)255; }

extern "C" void kernel_launch(void* const* d_in, const int* in_sizes, int n_in,
                              void* d_out, int out_size, void* d_ws, size_t ws_size,
                              hipStream_t stream) {
  const float* feature = (const float*)d_in[0];
  const int* adj_row   = (const int*)d_in[1];
  const int* adj_col   = (const int*)d_in[2];
  const float* adj_val = (const float*)d_in[3];
  const float* weight  = (const float*)d_in[4];
  float* out = (float*)d_out;

  const int N = in_sizes[0] / D;
  const int E = in_sizes[1];
  const size_t hbytes = (size_t)N * D * sizeof(float);

  // fast-path workspace layout
  char* p = (char*)d_ws;
  int* cnt      = (int*)p;   p += align256((size_t)N * 4);        // also cursor
  int* row_ptr  = (int*)p;   p += align256((size_t)(N + 1) * 4);
  int* csr_col  = (int*)p;   p += align256((size_t)E * 4);
  float* csr_val = (float*)p; p += align256((size_t)E * 4);
  float* h1     = (float*)p; p += align256(hbytes);
  const size_t need = (size_t)(p - (char*)d_ws);

  if (ws_size >= need) {
    hipMemsetAsync(cnt, 0, (size_t)N * 4, stream);
    hist_kernel<<<(E + 255) / 256, 256, 0, stream>>>(adj_row, cnt, E);
    scan_kernel<<<1, 1024, 0, stream>>>(cnt, row_ptr, cnt, N, E);
    scatter_kernel<<<(E + 255) / 256, 256, 0, stream>>>(adj_row, adj_col, adj_val,
                                                        cnt, csr_col, csr_val, E);
    // h1 = A @ feature
    spmm_csr_kernel<<<(N + 7) / 8, 256, 0, stream>>>(row_ptr, csr_col, csr_val,
                                                     feature, h1, N);
    // out = (0.5*(A@h1) - 0.5*feature) @ W
    fused_spmm2_gemm_kernel<<<(N + 31) / 32, 256, 0, stream>>>(
        row_ptr, csr_col, csr_val, h1, feature, weight, out, N);
  } else {
    // fallback: round-1 atomic pipeline (needs only h-buffer in ws)
    float* fh1 = out;
    float* fh2 = (float*)d_ws;
    const long items = (long)E * 32;
    const int spmm_blocks = (int)((items + 255) / 256);
    hipMemsetAsync(fh1, 0, hbytes, stream);
    spmm_atomic_kernel<<<spmm_blocks, 256, 0, stream>>>(adj_row, adj_col, adj_val,
                                                        feature, fh1, E);
    hipMemsetAsync(fh2, 0, hbytes, stream);
    spmm_atomic_kernel<<<spmm_blocks, 256, 0, stream>>>(adj_row, adj_col, adj_val,
                                                        fh1, fh2, E);
    combine_gemm_kernel<<<(N + 31) / 32, 256, 0, stream>>>(fh2, feature, weight,
                                                           out, N);
  }
}

// Round 3
// 318.268 us; speedup vs baseline: 8.6123x; 1.0184x over previous
//
#include <hip/hip_runtime.h>

#define D 128

// ---------------- helpers ----------------

__device__ __forceinline__ float4 gat(const float* __restrict__ x, int c, int q) {
  return *reinterpret_cast<const float4*>(x + ((long)c << 7) + (q << 2));
}
__device__ __forceinline__ void fma4(float4& a, float v, const float4& xv) {
  a.x = fmaf(v, xv.x, a.x);
  a.y = fmaf(v, xv.y, a.y);
  a.z = fmaf(v, xv.z, a.z);
  a.w = fmaf(v, xv.w, a.w);
}

// 8-deep prefetched row accumulation: acc = sum_{k in [s,e)} val_k * x[col_k][q*4..q*4+3]
__device__ __forceinline__ float4 row_accum(const int2* __restrict__ cv, int s, int e,
                                            const float* __restrict__ x, int q) {
  float4 acc = {0.f, 0.f, 0.f, 0.f};
  int k = s;
  const int e8 = s + ((e - s) & ~7);
  for (; k < e8; k += 8) {
    int2 c0 = cv[k + 0], c1 = cv[k + 1], c2 = cv[k + 2], c3 = cv[k + 3];
    int2 c4 = cv[k + 4], c5 = cv[k + 5], c6 = cv[k + 6], c7 = cv[k + 7];
    float4 x0 = gat(x, c0.x, q), x1 = gat(x, c1.x, q);
    float4 x2 = gat(x, c2.x, q), x3 = gat(x, c3.x, q);
    float4 x4 = gat(x, c4.x, q), x5 = gat(x, c5.x, q);
    float4 x6 = gat(x, c6.x, q), x7 = gat(x, c7.x, q);
    fma4(acc, __int_as_float(c0.y), x0);
    fma4(acc, __int_as_float(c1.y), x1);
    fma4(acc, __int_as_float(c2.y), x2);
    fma4(acc, __int_as_float(c3.y), x3);
    fma4(acc, __int_as_float(c4.y), x4);
    fma4(acc, __int_as_float(c5.y), x5);
    fma4(acc, __int_as_float(c6.y), x6);
    fma4(acc, __int_as_float(c7.y), x7);
  }
  for (; k < e; ++k) {
    int2 c = cv[k];
    float4 xv = gat(x, c.x, q);
    fma4(acc, __int_as_float(c.y), xv);
  }
  return acc;
}

// ---------------- CSR build ----------------

__global__ __launch_bounds__(256) void hist_kernel(const int* __restrict__ row,
                                                   int* __restrict__ cnt, int E) {
  int i = blockIdx.x * blockDim.x + threadIdx.x;
  if (i < E) atomicAdd(&cnt[row[i]], 1);
}

// single-block exclusive scan of cnt[N] -> row_ptr[N] (+row_ptr[N]=E) and cursor[N]
__global__ __launch_bounds__(1024) void scan_kernel(const int* __restrict__ cnt,
                                                    int* __restrict__ row_ptr,
                                                    int* __restrict__ cursor,
                                                    int N, int E) {
  __shared__ int wsum[16];
  __shared__ int s_carry;
  const int t = threadIdx.x;
  const int lane = t & 63;
  const int wave = t >> 6;
  if (t == 0) s_carry = 0;
  __syncthreads();
  for (int base = 0; base < N; base += 8192) {
    int v[8];
    int s = 0;
#pragma unroll
    for (int i = 0; i < 8; ++i) {
      int idx = base + t * 8 + i;
      v[i] = (idx < N) ? cnt[idx] : 0;
      s += v[i];
    }
    int x = s;
#pragma unroll
    for (int off = 1; off < 64; off <<= 1) {
      int y = __shfl_up(x, off, 64);
      if (lane >= off) x += y;
    }
    if (lane == 63) wsum[wave] = x;
    __syncthreads();
    if (wave == 0) {
      int ws = (lane < 16) ? wsum[lane] : 0;
      int xx = ws;
#pragma unroll
      for (int off = 1; off < 16; off <<= 1) {
        int y = __shfl_up(xx, off, 64);
        if (lane >= off) xx += y;
      }
      if (lane < 16) wsum[lane] = xx - ws;
    }
    __syncthreads();
    int carry = s_carry;
    int run = carry + wsum[wave] + (x - s);
#pragma unroll
    for (int i = 0; i < 8; ++i) {
      int idx = base + t * 8 + i;
      if (idx < N) { row_ptr[idx] = run; cursor[idx] = run; }
      run += v[i];
    }
    __syncthreads();
    if (t == 1023) s_carry = carry + wsum[15] + x;
    __syncthreads();
  }
  if (t == 0) row_ptr[N] = E;
}

__global__ __launch_bounds__(256) void scatter_kernel(
    const int* __restrict__ row, const int* __restrict__ col,
    const float* __restrict__ val, int* __restrict__ cursor,
    int2* __restrict__ csr_cv, int E) {
  int i = blockIdx.x * blockDim.x + threadIdx.x;
  if (i < E) {
    int r = row[i];
    int p = atomicAdd(&cursor[r], 1);
    csr_cv[p] = make_int2(col[i], __float_as_int(val[i]));
  }
}

// ---------------- CSR SpMM: y[r] = sum val*x[col] ----------------

__global__ __launch_bounds__(256) void spmm_csr_kernel(
    const int* __restrict__ row_ptr, const int2* __restrict__ csr_cv,
    const float* __restrict__ x, float* __restrict__ y, int N) {
  int r = blockIdx.x * (blockDim.x >> 5) + (threadIdx.x >> 5);
  int q = threadIdx.x & 31;
  if (r >= N) return;
  int s = row_ptr[r], e = row_ptr[r + 1];
  float4 acc = row_accum(csr_cv, s, e, x, q);
  *reinterpret_cast<float4*>(y + ((long)r << 7) + (q << 2)) = acc;
}

// ---------------- fused: out = (0.5*(A@h1) - 0.5*feat) @ W ----------------

__global__ __launch_bounds__(256) void fused_spmm2_gemm_kernel(
    const int* __restrict__ row_ptr, const int2* __restrict__ csr_cv,
    const float* __restrict__ h1, const float* __restrict__ feat,
    const float* __restrict__ W, float* __restrict__ out, int N) {
  __shared__ float zbuf[8][4][128];
  const int g = threadIdx.x >> 5;
  const int q = threadIdx.x & 31;
  const int row0 = blockIdx.x * 32 + g * 4;

#pragma unroll
  for (int rr = 0; rr < 4; ++rr) {
    int r = row0 + rr;
    float4 acc = {0.f, 0.f, 0.f, 0.f};
    if (r < N) {
      int s = row_ptr[r], e = row_ptr[r + 1];
      acc = row_accum(csr_cv, s, e, h1, q);
      float4 fv = *reinterpret_cast<const float4*>(feat + ((long)r << 7) + (q << 2));
      acc.x = 0.5f * (acc.x - fv.x);
      acc.y = 0.5f * (acc.y - fv.y);
      acc.z = 0.5f * (acc.z - fv.z);
      acc.w = 0.5f * (acc.w - fv.w);
    }
    *reinterpret_cast<float4*>(&zbuf[g][rr][q * 4]) = acc;
  }
  __syncthreads();

  const int j0 = q * 4;
  float4 o[4];
#pragma unroll
  for (int rr = 0; rr < 4; ++rr) o[rr] = {0.f, 0.f, 0.f, 0.f};
#pragma unroll 4
  for (int k = 0; k < D; ++k) {
    float4 wv = *reinterpret_cast<const float4*>(W + k * D + j0);
#pragma unroll
    for (int rr = 0; rr < 4; ++rr) {
      float zv = zbuf[g][rr][k];
      o[rr].x = fmaf(zv, wv.x, o[rr].x);
      o[rr].y = fmaf(zv, wv.y, o[rr].y);
      o[rr].z = fmaf(zv, wv.z, o[rr].z);
      o[rr].w = fmaf(zv, wv.w, o[rr].w);
    }
  }
#pragma unroll
  for (int rr = 0; rr < 4; ++rr) {
    int r = row0 + rr;
    if (r < N) *reinterpret_cast<float4*>(out + ((long)r << 7) + j0) = o[rr];
  }
}

// ---------------- fallback (round-1) kernels ----------------

__global__ __launch_bounds__(256) void spmm_atomic_kernel(
    const int* __restrict__ row, const int* __restrict__ col,
    const float* __restrict__ val, const float* __restrict__ x,
    float* __restrict__ y, int E) {
  long idx = (long)blockIdx.x * blockDim.x + threadIdx.x;
  int e = (int)(idx >> 5);
  if (e >= E) return;
  int q = (int)(idx & 31);
  int r = row[e];
  int c = col[e];
  float v = val[e];
  const float4 xv = *reinterpret_cast<const float4*>(x + (long)c * D + q * 4);
  float* yp = y + (long)r * D + q * 4;
  atomicAdd(yp + 0, v * xv.x);
  atomicAdd(yp + 1, v * xv.y);
  atomicAdd(yp + 2, v * xv.z);
  atomicAdd(yp + 3, v * xv.w);
}

__global__ __launch_bounds__(256) void combine_gemm_kernel(
    const float* __restrict__ h2, const float* __restrict__ feat,
    const float* __restrict__ W, float* __restrict__ out, int N) {
  __shared__ float Ws[D][D];
  __shared__ float Xs[32][D];
  const int t = threadIdx.x;
#pragma unroll
  for (int i = 0; i < 16; ++i) {
    int o = i * 1024 + t * 4;
    *reinterpret_cast<float4*>(&Ws[0][0] + o) =
        *reinterpret_cast<const float4*>(W + o);
  }
  const int rb = blockIdx.x * 32;
#pragma unroll
  for (int i = 0; i < 4; ++i) {
    int o = i * 1024 + t * 4;
    int r = o >> 7;
    int cc = o & 127;
    float4 xv = {0.f, 0.f, 0.f, 0.f};
    if (rb + r < N) {
      float4 hv = *reinterpret_cast<const float4*>(h2 + (long)(rb + r) * D + cc);
      float4 fv = *reinterpret_cast<const float4*>(feat + (long)(rb + r) * D + cc);
      xv.x = 0.5f * (hv.x - fv.x);
      xv.y = 0.5f * (hv.y - fv.y);
      xv.z = 0.5f * (hv.z - fv.z);
      xv.w = 0.5f * (hv.w - fv.w);
    }
    *reinterpret_cast<float4*>(&Xs[r][cc]) = xv;
  }
  __syncthreads();
  const int j0 = (t & 31) * 4;
  const int i0 = (t >> 5) * 4;
  float4 acc[4];
#pragma unroll
  for (int ii = 0; ii < 4; ++ii) acc[ii] = {0.f, 0.f, 0.f, 0.f};
#pragma unroll 8
  for (int kb = 0; kb < 32; ++kb) {
    float4 xr[4], wr[4];
#pragma unroll
    for (int ii = 0; ii < 4; ++ii)
      xr[ii] = *reinterpret_cast<const float4*>(&Xs[i0 + ii][kb * 4]);
#pragma unroll
    for (int kk = 0; kk < 4; ++kk)
      wr[kk] = *reinterpret_cast<const float4*>(&Ws[kb * 4 + kk][j0]);
#pragma unroll
    for (int ii = 0; ii < 4; ++ii) {
      const float* xp = &xr[ii].x;
#pragma unroll
      for (int kk = 0; kk < 4; ++kk) {
        float xk = xp[kk];
        acc[ii].x += xk * wr[kk].x;
        acc[ii].y += xk * wr[kk].y;
        acc[ii].z += xk * wr[kk].z;
        acc[ii].w += xk * wr[kk].w;
      }
    }
  }
#pragma unroll
  for (int ii = 0; ii < 4; ++ii) {
    int r = rb + i0 + ii;
    if (r < N)
      *reinterpret_cast<float4*>(out + (long)r * D + j0) = acc[ii];
  }
}

// ---------------- host ----------------

static inline size_t align256(size_t x) { return (x + 255) & ~(size_t)255; }

extern "C" void kernel_launch(void* const* d_in, const int* in_sizes, int n_in,
                              void* d_out, int out_size, void* d_ws, size_t ws_size,
                              hipStream_t stream) {
  const float* feature = (const float*)d_in[0];
  const int* adj_row   = (const int*)d_in[1];
  const int* adj_col   = (const int*)d_in[2];
  const float* adj_val = (const float*)d_in[3];
  const float* weight  = (const float*)d_in[4];
  float* out = (float*)d_out;

  const int N = in_sizes[0] / D;
  const int E = in_sizes[1];
  const size_t hbytes = (size_t)N * D * sizeof(float);

  char* p = (char*)d_ws;
  int* cnt      = (int*)p;   p += align256((size_t)N * 4);  // also cursor
  int* row_ptr  = (int*)p;   p += align256((size_t)(N + 1) * 4);
  int2* csr_cv  = (int2*)p;  p += align256((size_t)E * 8);
  float* h1     = (float*)p; p += align256(hbytes);
  const size_t need = (size_t)(p - (char*)d_ws);

  if (ws_size >= need) {
    hipMemsetAsync(cnt, 0, (size_t)N * 4, stream);
    hist_kernel<<<(E + 255) / 256, 256, 0, stream>>>(adj_row, cnt, E);
    scan_kernel<<<1, 1024, 0, stream>>>(cnt, row_ptr, cnt, N, E);
    scatter_kernel<<<(E + 255) / 256, 256, 0, stream>>>(adj_row, adj_col, adj_val,
                                                        cnt, csr_cv, E);
    spmm_csr_kernel<<<(N + 7) / 8, 256, 0, stream>>>(row_ptr, csr_cv, feature, h1, N);
    fused_spmm2_gemm_kernel<<<(N + 31) / 32, 256, 0, stream>>>(
        row_ptr, csr_cv, h1, feature, weight, out, N);
  } else {
    float* fh1 = out;
    float* fh2 = (float*)d_ws;
    const long items = (long)E * 32;
    const int spmm_blocks = (int)((items + 255) / 256);
    hipMemsetAsync(fh1, 0, hbytes, stream);
    spmm_atomic_kernel<<<spmm_blocks, 256, 0, stream>>>(adj_row, adj_col, adj_val,
                                                        feature, fh1, E);
    hipMemsetAsync(fh2, 0, hbytes, stream);
    spmm_atomic_kernel<<<spmm_blocks, 256, 0, stream>>>(adj_row, adj_col, adj_val,
                                                        fh1, fh2, E);
    combine_gemm_kernel<<<(N + 31) / 32, 256, 0, stream>>>(fh2, feature, weight,
                                                           out, N);
  }
}

// Round 4
// 303.740 us; speedup vs baseline: 9.0242x; 1.0478x over previous
//
#include <hip/hip_runtime.h>
#include <hip/hip_fp16.h>

#define D 128

// ---------------- helpers ----------------

// acc += val_k * xh[col_k][q*4..q*4+3]  (fp16 gathered operand, fp32 accum)
__device__ __forceinline__ float4 row_accum_h(const int2* __restrict__ cv, int s, int e,
                                              const __half* __restrict__ xh, int q) {
  float4 acc = {0.f, 0.f, 0.f, 0.f};
  for (int k = s; k < e; ++k) {
    int2 c = cv[k];
    uint2 u = *reinterpret_cast<const uint2*>(xh + ((long)c.x << 7) + (q << 2));
    float v = __int_as_float(c.y);
    __half2 h0 = *reinterpret_cast<__half2*>(&u.x);
    __half2 h1 = *reinterpret_cast<__half2*>(&u.y);
    float2 f0 = __half22float2(h0);
    float2 f1 = __half22float2(h1);
    acc.x = fmaf(v, f0.x, acc.x);
    acc.y = fmaf(v, f0.y, acc.y);
    acc.z = fmaf(v, f1.x, acc.z);
    acc.w = fmaf(v, f1.y, acc.w);
  }
  return acc;
}

// ---------------- feature -> fp16 copy ----------------

__global__ __launch_bounds__(256) void convert_kernel(const float* __restrict__ x,
                                                      __half* __restrict__ xh,
                                                      long n8) {
  long i = (long)blockIdx.x * blockDim.x + threadIdx.x;
  if (i >= n8) return;
  const float4* src = reinterpret_cast<const float4*>(x) + i * 2;
  float4 a = src[0], b = src[1];
  __half2 h0 = __floats2half2_rn(a.x, a.y);
  __half2 h1 = __floats2half2_rn(a.z, a.w);
  __half2 h2 = __floats2half2_rn(b.x, b.y);
  __half2 h3 = __floats2half2_rn(b.z, b.w);
  uint4 st;
  st.x = *reinterpret_cast<uint*>(&h0);
  st.y = *reinterpret_cast<uint*>(&h1);
  st.z = *reinterpret_cast<uint*>(&h2);
  st.w = *reinterpret_cast<uint*>(&h3);
  *(reinterpret_cast<uint4*>(xh) + i) = st;
}

// ---------------- CSR build ----------------

__global__ __launch_bounds__(256) void hist_kernel(const int* __restrict__ row,
                                                   int* __restrict__ cnt, int E) {
  int i = blockIdx.x * blockDim.x + threadIdx.x;
  if (i < E) atomicAdd(&cnt[row[i]], 1);
}

__global__ __launch_bounds__(1024) void scan_kernel(const int* __restrict__ cnt,
                                                    int* __restrict__ row_ptr,
                                                    int* __restrict__ cursor,
                                                    int N, int E) {
  __shared__ int wsum[16];
  __shared__ int s_carry;
  const int t = threadIdx.x;
  const int lane = t & 63;
  const int wave = t >> 6;
  if (t == 0) s_carry = 0;
  __syncthreads();
  for (int base = 0; base < N; base += 8192) {
    int v[8];
    int s = 0;
#pragma unroll
    for (int i = 0; i < 8; ++i) {
      int idx = base + t * 8 + i;
      v[i] = (idx < N) ? cnt[idx] : 0;
      s += v[i];
    }
    int x = s;
#pragma unroll
    for (int off = 1; off < 64; off <<= 1) {
      int y = __shfl_up(x, off, 64);
      if (lane >= off) x += y;
    }
    if (lane == 63) wsum[wave] = x;
    __syncthreads();
    if (wave == 0) {
      int ws = (lane < 16) ? wsum[lane] : 0;
      int xx = ws;
#pragma unroll
      for (int off = 1; off < 16; off <<= 1) {
        int y = __shfl_up(xx, off, 64);
        if (lane >= off) xx += y;
      }
      if (lane < 16) wsum[lane] = xx - ws;
    }
    __syncthreads();
    int carry = s_carry;
    int run = carry + wsum[wave] + (x - s);
#pragma unroll
    for (int i = 0; i < 8; ++i) {
      int idx = base + t * 8 + i;
      if (idx < N) { row_ptr[idx] = run; cursor[idx] = run; }
      run += v[i];
    }
    __syncthreads();
    if (t == 1023) s_carry = carry + wsum[15] + x;
    __syncthreads();
  }
  if (t == 0) row_ptr[N] = E;
}

__global__ __launch_bounds__(256) void scatter_kernel(
    const int* __restrict__ row, const int* __restrict__ col,
    const float* __restrict__ val, int* __restrict__ cursor,
    int2* __restrict__ csr_cv, int E) {
  int i = blockIdx.x * blockDim.x + threadIdx.x;
  if (i < E) {
    int r = row[i];
    int p = atomicAdd(&cursor[r], 1);
    csr_cv[p] = make_int2(col[i], __float_as_int(val[i]));
  }
}

// ---------------- SpMM1: h1 (fp16) = A @ feature(fp16) ----------------

__global__ __launch_bounds__(256) void spmm_csr_h_kernel(
    const int* __restrict__ row_ptr, const int2* __restrict__ csr_cv,
    const __half* __restrict__ xh, __half* __restrict__ y, int N) {
  int r = blockIdx.x * (blockDim.x >> 5) + (threadIdx.x >> 5);
  int q = threadIdx.x & 31;
  if (r >= N) return;
  int s = row_ptr[r], e = row_ptr[r + 1];
  float4 acc = row_accum_h(csr_cv, s, e, xh, q);
  __half2 p0 = __floats2half2_rn(acc.x, acc.y);
  __half2 p1 = __floats2half2_rn(acc.z, acc.w);
  uint2 st;
  st.x = *reinterpret_cast<uint*>(&p0);
  st.y = *reinterpret_cast<uint*>(&p1);
  *reinterpret_cast<uint2*>(y + ((long)r << 7) + (q << 2)) = st;
}

// ---------------- fused: out = (0.5*(A@h1) - 0.5*feat) @ W ----------------

__global__ __launch_bounds__(256) void fused_spmm2_gemm_kernel(
    const int* __restrict__ row_ptr, const int2* __restrict__ csr_cv,
    const __half* __restrict__ h1, const float* __restrict__ feat,
    const float* __restrict__ W, float* __restrict__ out, int N) {
  __shared__ float zbuf[8][4][128];
  const int g = threadIdx.x >> 5;
  const int q = threadIdx.x & 31;
  const int row0 = blockIdx.x * 32 + g * 4;

#pragma unroll
  for (int rr = 0; rr < 4; ++rr) {
    int r = row0 + rr;
    float4 acc = {0.f, 0.f, 0.f, 0.f};
    if (r < N) {
      int s = row_ptr[r], e = row_ptr[r + 1];
      acc = row_accum_h(csr_cv, s, e, h1, q);
      float4 fv = *reinterpret_cast<const float4*>(feat + ((long)r << 7) + (q << 2));
      acc.x = 0.5f * (acc.x - fv.x);
      acc.y = 0.5f * (acc.y - fv.y);
      acc.z = 0.5f * (acc.z - fv.z);
      acc.w = 0.5f * (acc.w - fv.w);
    }
    *reinterpret_cast<float4*>(&zbuf[g][rr][q * 4]) = acc;
  }
  __syncthreads();

  const int j0 = q * 4;
  float4 o[4];
#pragma unroll
  for (int rr = 0; rr < 4; ++rr) o[rr] = {0.f, 0.f, 0.f, 0.f};
#pragma unroll 4
  for (int k = 0; k < D; ++k) {
    float4 wv = *reinterpret_cast<const float4*>(W + k * D + j0);
#pragma unroll
    for (int rr = 0; rr < 4; ++rr) {
      float zv = zbuf[g][rr][k];
      o[rr].x = fmaf(zv, wv.x, o[rr].x);
      o[rr].y = fmaf(zv, wv.y, o[rr].y);
      o[rr].z = fmaf(zv, wv.z, o[rr].z);
      o[rr].w = fmaf(zv, wv.w, o[rr].w);
    }
  }
#pragma unroll
  for (int rr = 0; rr < 4; ++rr) {
    int r = row0 + rr;
    if (r < N) *reinterpret_cast<float4*>(out + ((long)r << 7) + j0) = o[rr];
  }
}

// ---------------- fallback (round-1) kernels ----------------

__global__ __launch_bounds__(256) void spmm_atomic_kernel(
    const int* __restrict__ row, const int* __restrict__ col,
    const float* __restrict__ val, const float* __restrict__ x,
    float* __restrict__ y, int E) {
  long idx = (long)blockIdx.x * blockDim.x + threadIdx.x;
  int e = (int)(idx >> 5);
  if (e >= E) return;
  int q = (int)(idx & 31);
  int r = row[e];
  int c = col[e];
  float v = val[e];
  const float4 xv = *reinterpret_cast<const float4*>(x + (long)c * D + q * 4);
  float* yp = y + (long)r * D + q * 4;
  atomicAdd(yp + 0, v * xv.x);
  atomicAdd(yp + 1, v * xv.y);
  atomicAdd(yp + 2, v * xv.z);
  atomicAdd(yp + 3, v * xv.w);
}

__global__ __launch_bounds__(256) void combine_gemm_kernel(
    const float* __restrict__ h2, const float* __restrict__ feat,
    const float* __restrict__ W, float* __restrict__ out, int N) {
  __shared__ float Ws[D][D];
  __shared__ float Xs[32][D];
  const int t = threadIdx.x;
#pragma unroll
  for (int i = 0; i < 16; ++i) {
    int o = i * 1024 + t * 4;
    *reinterpret_cast<float4*>(&Ws[0][0] + o) =
        *reinterpret_cast<const float4*>(W + o);
  }
  const int rb = blockIdx.x * 32;
#pragma unroll
  for (int i = 0; i < 4; ++i) {
    int o = i * 1024 + t * 4;
    int r = o >> 7;
    int cc = o & 127;
    float4 xv = {0.f, 0.f, 0.f, 0.f};
    if (rb + r < N) {
      float4 hv = *reinterpret_cast<const float4*>(h2 + (long)(rb + r) * D + cc);
      float4 fv = *reinterpret_cast<const float4*>(feat + (long)(rb + r) * D + cc);
      xv.x = 0.5f * (hv.x - fv.x);
      xv.y = 0.5f * (hv.y - fv.y);
      xv.z = 0.5f * (hv.z - fv.z);
      xv.w = 0.5f * (hv.w - fv.w);
    }
    *reinterpret_cast<float4*>(&Xs[r][cc]) = xv;
  }
  __syncthreads();
  const int j0 = (t & 31) * 4;
  const int i0 = (t >> 5) * 4;
  float4 acc[4];
#pragma unroll
  for (int ii = 0; ii < 4; ++ii) acc[ii] = {0.f, 0.f, 0.f, 0.f};
#pragma unroll 8
  for (int kb = 0; kb < 32; ++kb) {
    float4 xr[4], wr[4];
#pragma unroll
    for (int ii = 0; ii < 4; ++ii)
      xr[ii] = *reinterpret_cast<const float4*>(&Xs[i0 + ii][kb * 4]);
#pragma unroll
    for (int kk = 0; kk < 4; ++kk)
      wr[kk] = *reinterpret_cast<const float4*>(&Ws[kb * 4 + kk][j0]);
#pragma unroll
    for (int ii = 0; ii < 4; ++ii) {
      const float* xp = &xr[ii].x;
#pragma unroll
      for (int kk = 0; kk < 4; ++kk) {
        float xk = xp[kk];
        acc[ii].x += xk * wr[kk].x;
        acc[ii].y += xk * wr[kk].y;
        acc[ii].z += xk * wr[kk].z;
        acc[ii].w += xk * wr[kk].w;
      }
    }
  }
#pragma unroll
  for (int ii = 0; ii < 4; ++ii) {
    int r = rb + i0 + ii;
    if (r < N)
      *reinterpret_cast<float4*>(out + (long)r * D + j0) = acc[ii];
  }
}

// ---------------- host ----------------

static inline size_t align256(size_t x) { return (x + 255) & ~(size_t)255; }

extern "C" void kernel_launch(void* const* d_in, const int* in_sizes, int n_in,
                              void* d_out, int out_size, void* d_ws, size_t ws_size,
                              hipStream_t stream) {
  const float* feature = (const float*)d_in[0];
  const int* adj_row   = (const int*)d_in[1];
  const int* adj_col   = (const int*)d_in[2];
  const float* adj_val = (const float*)d_in[3];
  const float* weight  = (const float*)d_in[4];
  float* out = (float*)d_out;

  const int N = in_sizes[0] / D;
  const int E = in_sizes[1];
  const size_t hbytes  = (size_t)N * D * sizeof(float);
  const size_t hbytes2 = (size_t)N * D * sizeof(__half);

  char* p = (char*)d_ws;
  int* cnt       = (int*)p;    p += align256((size_t)N * 4);  // also cursor
  int* row_ptr   = (int*)p;    p += align256((size_t)(N + 1) * 4);
  int2* csr_cv   = (int2*)p;   p += align256((size_t)E * 8);
  __half* feath  = (__half*)p; p += align256(hbytes2);
  __half* h1h    = (__half*)p; p += align256(hbytes2);
  const size_t need = (size_t)(p - (char*)d_ws);

  if (ws_size >= need) {
    hipMemsetAsync(cnt, 0, (size_t)N * 4, stream);
    const long n8 = (long)N * D / 8;
    convert_kernel<<<(int)((n8 + 255) / 256), 256, 0, stream>>>(feature, feath, n8);
    hist_kernel<<<(E + 255) / 256, 256, 0, stream>>>(adj_row, cnt, E);
    scan_kernel<<<1, 1024, 0, stream>>>(cnt, row_ptr, cnt, N, E);
    scatter_kernel<<<(E + 255) / 256, 256, 0, stream>>>(adj_row, adj_col, adj_val,
                                                        cnt, csr_cv, E);
    // h1(fp16) = A @ feature(fp16)
    spmm_csr_h_kernel<<<(N + 7) / 8, 256, 0, stream>>>(row_ptr, csr_cv, feath, h1h, N);
    // out = (0.5*(A@h1) - 0.5*feature) @ W
    fused_spmm2_gemm_kernel<<<(N + 31) / 32, 256, 0, stream>>>(
        row_ptr, csr_cv, h1h, feature, weight, out, N);
  } else {
    float* fh1 = out;
    float* fh2 = (float*)d_ws;
    const long items = (long)E * 32;
    const int spmm_blocks = (int)((items + 255) / 256);
    hipMemsetAsync(fh1, 0, hbytes, stream);
    spmm_atomic_kernel<<<spmm_blocks, 256, 0, stream>>>(adj_row, adj_col, adj_val,
                                                        feature, fh1, E);
    hipMemsetAsync(fh2, 0, hbytes, stream);
    spmm_atomic_kernel<<<spmm_blocks, 256, 0, stream>>>(adj_row, adj_col, adj_val,
                                                        fh1, fh2, E);
    combine_gemm_kernel<<<(N + 31) / 32, 256, 0, stream>>>(fh2, feature, weight,
                                                           out, N);
  }
}